// Round 1
// baseline (246.268 us; speedup 1.0000x reference)
//
#include <hip/hip_runtime.h>
#include <hip/hip_bf16.h>

// h = x(65536x512) @ W^T(512x256) + bias_lin ; GroupNorm(8 groups of 32)
// ; min over 256 channels -> m[b] ; out[c*B+b] = m[b] + bias[c]
//
// Persistent design: grid=1024 blocks x 512 threads (8 waves) = 4 blocks/CU
// (LDS 34816B x4 = 136KB <= 160KB; 2048 threads/CU). Wave w owns channel
// group w (cols 32w..32w+31) and holds ALL its W fragments in registers
// (32 short8 = 128 VGPRs), loaded once. K-loop = ds_read + MFMA only.
// Each block loops over 2 row-tiles of 32, prefetching the next x tile
// into registers while computing the current one. 4 blocks/CU gives the
// scheduler other waves to run during each block's barrier/HBM stalls
// (R0 fix: grid=256 was 1 block/CU -> 19% occupancy, 21% HBM).
#define B_ROWS 65536
#define K_DIM  512
#define N_DIM  256
#define EPS    1e-5f
#define MTILE  32
#define NBLK   1024
#define STRIDE 520      // 512 + 8 pad (bf16 elems); 1040B rows -> 2-way alias max (free)

using short8  = __attribute__((ext_vector_type(8))) short;
using floatx4 = __attribute__((ext_vector_type(4))) float;

__device__ __forceinline__ unsigned short f2bf(float f) {
    unsigned u = __builtin_bit_cast(unsigned, f);
    u += 0x7FFFu + ((u >> 16) & 1u);     // RNE
    return (unsigned short)(u >> 16);
}

// Pack W (256x512 fp32) into bf16 MFMA B-fragment order:
// P[((nt*16 + kkg)*64 + lane)*8 + j] = bf16(W[nt*16 + (lane&15)][kkg*32 + (lane>>4)*8 + j])
__global__ __launch_bounds__(64) void pack_w(const float* __restrict__ W,
                                             unsigned short* __restrict__ P) {
    int b    = blockIdx.x;           // 0..255
    int nt   = b >> 4, kk = b & 15;
    int lane = threadIdx.x;
    int l15  = lane & 15, quad = lane >> 4;
    const float* src = W + (size_t)(nt * 16 + l15) * K_DIM + kk * 32 + quad * 8;
    short8 v;
#pragma unroll
    for (int j = 0; j < 8; ++j) v[j] = (short)f2bf(src[j]);
    *(short8*)(P + ((size_t)(nt * 16 + kk) * 64 + lane) * 8) = v;
}

__global__ __launch_bounds__(512, 2) void fused_persistent(
    const float* __restrict__ X, const unsigned short* __restrict__ P,
    const float* __restrict__ bias_lin, const float* __restrict__ wgn,
    const float* __restrict__ bgn, const float* __restrict__ bias,
    float* __restrict__ out)
{
    __shared__ unsigned short Ash[MTILE * STRIDE];   // 33280 B
    __shared__ float sm_min[8][MTILE];               // 1024 B
    __shared__ float m_sh[MTILE];                    // 128 B

    const int tid  = threadIdx.x;
    const int wave = tid >> 6, lane = tid & 63;
    const int l15  = lane & 15, quad = lane >> 4;

    // ---- load ALL of this wave's W fragments into registers (once) ----
    short8 bfr[2][16];
#pragma unroll
    for (int ct = 0; ct < 2; ++ct)
#pragma unroll
        for (int kkg = 0; kkg < 16; ++kkg) {
            int nt = 2 * wave + ct;
            bfr[ct][kkg] = *(const short8*)(P + (((size_t)nt * 16 + kkg) * 64 + lane) * 8);
        }

    // per-column params (hoisted; col = wave*32 + ct*16 + l15)
    float bl[2], wg[2], bg[2];
#pragma unroll
    for (int ct = 0; ct < 2; ++ct) {
        int col = wave * 32 + ct * 16 + l15;
        bl[ct] = bias_lin[col]; wg[ct] = wgn[col]; bg[ct] = bgn[col];
    }
    // bcast-channel biases (c = pass*64 + (tid>>3))
    float bias_r[4];
#pragma unroll
    for (int pass = 0; pass < 4; ++pass) bias_r[pass] = bias[pass * 64 + (tid >> 3)];

    // staging geometry: tile = 32 rows x 128 float4; thread covers
    // rows r0+4p (r0 = tid>>7), cols [c4, c4+4) fp32 (c4 = (tid&127)*4)
    const int r0 = tid >> 7;
    const int c4 = (tid & 127) * 4;

    const int tiles = B_ROWS / MTILE;    // 2048
    int t = blockIdx.x;

    // prefetch tile 0
    float4 xq[8];
#pragma unroll
    for (int p = 0; p < 8; ++p)
        xq[p] = *(const float4*)(X + (size_t)(t * MTILE + r0 + 4 * p) * K_DIM + c4);

    for (; t < tiles; t += NBLK) {
        // ---- convert + stage into LDS ----
#pragma unroll
        for (int p = 0; p < 8; ++p) {
            ushort4 h;
            h.x = f2bf(xq[p].x); h.y = f2bf(xq[p].y);
            h.z = f2bf(xq[p].z); h.w = f2bf(xq[p].w);
            *(ushort4*)(&Ash[(r0 + 4 * p) * STRIDE + c4]) = h;
        }
        __syncthreads();

        // ---- prefetch next tile (overlaps compute + epilogue) ----
        int tn = t + NBLK;
        if (tn < tiles) {
#pragma unroll
            for (int p = 0; p < 8; ++p)
                xq[p] = *(const float4*)(X + (size_t)(tn * MTILE + r0 + 4 * p) * K_DIM + c4);
        }

        // ---- K-loop: pure LDS + MFMA ----
        floatx4 acc[2][2] = {};
#pragma unroll
        for (int kk = 0; kk < 16; ++kk) {
            short8 a0 = *(const short8*)&Ash[(l15)      * STRIDE + kk * 32 + quad * 8];
            short8 a1 = *(const short8*)&Ash[(16 + l15) * STRIDE + kk * 32 + quad * 8];
            acc[0][0] = __builtin_amdgcn_mfma_f32_16x16x32_bf16(a0, bfr[0][kk], acc[0][0], 0, 0, 0);
            acc[0][1] = __builtin_amdgcn_mfma_f32_16x16x32_bf16(a0, bfr[1][kk], acc[0][1], 0, 0, 0);
            acc[1][0] = __builtin_amdgcn_mfma_f32_16x16x32_bf16(a1, bfr[0][kk], acc[1][0], 0, 0, 0);
            acc[1][1] = __builtin_amdgcn_mfma_f32_16x16x32_bf16(a1, bfr[1][kk], acc[1][1], 0, 0, 0);
        }

        // ---- epilogue: bias + groupnorm (group = this wave's 32 cols) + min ----
#pragma unroll
        for (int rt = 0; rt < 2; ++rt) {
#pragma unroll
            for (int reg = 0; reg < 4; ++reg) {
                float va = acc[rt][0][reg] + bl[0];
                float vb = acc[rt][1][reg] + bl[1];
                float s = va + vb, ss = va * va + vb * vb;
#pragma unroll
                for (int m = 1; m < 16; m <<= 1) {   // 16-lane butterfly (in-quad)
                    s  += __shfl_xor(s, m);
                    ss += __shfl_xor(ss, m);
                }
                float mean = s * (1.0f / 32.0f);
                float var  = ss * (1.0f / 32.0f) - mean * mean;
                float inv  = rsqrtf(var + EPS);
                float ga = (va - mean) * inv * wg[0] + bg[0];
                float gb = (vb - mean) * inv * wg[1] + bg[1];
                float mn = fminf(ga, gb);
#pragma unroll
                for (int m = 1; m < 16; m <<= 1) mn = fminf(mn, __shfl_xor(mn, m));
                if (l15 == 0) sm_min[wave][rt * 16 + quad * 4 + reg] = mn;
            }
        }
        __syncthreads();
        if (tid < MTILE) {
            float m0 = sm_min[0][tid];
#pragma unroll
            for (int w = 1; w < 8; ++w) m0 = fminf(m0, sm_min[w][tid]);
            m_sh[tid] = m0;
        }
        __syncthreads();

        // ---- broadcast write: out[c*B + t*32 + j] = m[j] + bias[c] ----
        float4 mv = *(const float4*)&m_sh[(tid & 7) * 4];
#pragma unroll
        for (int pass = 0; pass < 4; ++pass) {
            int c = pass * 64 + (tid >> 3);
            float bc = bias_r[pass];
            float4 o;
            o.x = mv.x + bc; o.y = mv.y + bc; o.z = mv.z + bc; o.w = mv.w + bc;
            *(float4*)(out + (size_t)c * B_ROWS + t * MTILE + (tid & 7) * 4) = o;
        }
        // next iteration's Ash write is safe: every wave passed the two
        // epilogue barriers, which postdate all Ash reads.
    }
}

extern "C" void kernel_launch(void* const* d_in, const int* in_sizes, int n_in,
                              void* d_out, int out_size, void* d_ws, size_t ws_size,
                              hipStream_t stream) {
    const float* x    = (const float*)d_in[0];
    const float* w    = (const float*)d_in[1];
    const float* bl   = (const float*)d_in[2];
    const float* wg   = (const float*)d_in[3];
    const float* bg   = (const float*)d_in[4];
    const float* bias = (const float*)d_in[5];

    unsigned short* P = (unsigned short*)d_ws;     // 256 KB packed bf16 W
    float* out = (float*)d_out;

    hipLaunchKernelGGL(pack_w, dim3(256), dim3(64), 0, stream, w, P);
    hipLaunchKernelGGL(fused_persistent, dim3(NBLK), dim3(512), 0, stream,
                       x, P, bl, wg, bg, bias, out);
}

// Round 3
// 232.571 us; speedup vs baseline: 1.0589x; 1.0589x over previous
//
#include <hip/hip_runtime.h>
#include <hip/hip_bf16.h>

// h = x(65536x512) @ W^T(512x256) + bias_lin ; GroupNorm(8 groups of 32)
// ; min over 256 channels -> m[b] ; out[c*B+b] = m[b] + bias[c]
//
// Persistent design: grid=512 blocks x 512 threads (8 waves) = 2 blocks/CU.
// Wave w owns channel group w (cols 32w..32w+31), W fragments in registers.
//
// R2 change (theory: LDS-crossbar serialization): MFMA computes D = W·X^T
// (A=W-frag, B=X-frag; P packing is layout-symmetric so bytes unchanged).
// Lane now holds 8 CHANNELS of one row (ch=ct*16+quad*4+reg, row=rt*16+l15),
// so GroupNorm stats are 7 in-lane adds + 2 shfl_xor(16/32) instead of a
// 16-lane butterfly per acc register: 96 -> 12 shuffles per wave per tile.
// bias_lin folds into the MFMA C-init.
// (R2 bench was an infra failure — resubmitted unchanged.)
#define B_ROWS 65536
#define K_DIM  512
#define N_DIM  256
#define EPS    1e-5f
#define MTILE  32
#define NBLK   512
#define STRIDE 520      // 512 + 8 pad (bf16); dword-stride 260 -> 8 lanes/bank-group = conflict-free b128

using short8  = __attribute__((ext_vector_type(8))) short;
using floatx4 = __attribute__((ext_vector_type(4))) float;

__device__ __forceinline__ unsigned short f2bf(float f) {
    unsigned u = __builtin_bit_cast(unsigned, f);
    u += 0x7FFFu + ((u >> 16) & 1u);     // RNE
    return (unsigned short)(u >> 16);
}

// Pack W (256x512 fp32) into bf16 MFMA fragment order (A- and B-layouts are
// symmetric for 16x16x32):
// P[((nt*16 + kkg)*64 + lane)*8 + j] = bf16(W[nt*16 + (lane&15)][kkg*32 + (lane>>4)*8 + j])
__global__ __launch_bounds__(64) void pack_w(const float* __restrict__ W,
                                             unsigned short* __restrict__ P) {
    int b    = blockIdx.x;           // 0..255
    int nt   = b >> 4, kk = b & 15;
    int lane = threadIdx.x;
    int l15  = lane & 15, quad = lane >> 4;
    const float* src = W + (size_t)(nt * 16 + l15) * K_DIM + kk * 32 + quad * 8;
    short8 v;
#pragma unroll
    for (int j = 0; j < 8; ++j) v[j] = (short)f2bf(src[j]);
    *(short8*)(P + ((size_t)(nt * 16 + kk) * 64 + lane) * 8) = v;
}

__global__ __launch_bounds__(512, 2) void fused_persistent(
    const float* __restrict__ X, const unsigned short* __restrict__ P,
    const float* __restrict__ bias_lin, const float* __restrict__ wgn,
    const float* __restrict__ bgn, const float* __restrict__ bias,
    float* __restrict__ out)
{
    __shared__ unsigned short Ash[MTILE * STRIDE];   // 33280 B
    __shared__ float sm_min[8][MTILE];               // 1024 B
    __shared__ float m_sh[MTILE];                    // 128 B

    const int tid  = threadIdx.x;
    const int wave = tid >> 6, lane = tid & 63;
    const int l15  = lane & 15, quad = lane >> 4;

    // ---- load ALL of this wave's W fragments into registers (once) ----
    short8 bfr[2][16];
#pragma unroll
    for (int ct = 0; ct < 2; ++ct)
#pragma unroll
        for (int kkg = 0; kkg < 16; ++kkg) {
            int nt = 2 * wave + ct;
            bfr[ct][kkg] = *(const short8*)(P + (((size_t)nt * 16 + kkg) * 64 + lane) * 8);
        }

    // per-lane channel params: lane's 8 channels are ch = wave*32 + ct*16 + quad*4 + reg
    float blr[2][4], wgr[2][4], bgr[2][4];
#pragma unroll
    for (int ct = 0; ct < 2; ++ct)
#pragma unroll
        for (int reg = 0; reg < 4; ++reg) {
            int c = wave * 32 + ct * 16 + quad * 4 + reg;
            blr[ct][reg] = bias_lin[c];
            wgr[ct][reg] = wgn[c];
            bgr[ct][reg] = bgn[c];
        }
    // bcast-channel biases (c = pass*64 + (tid>>3))
    float bias_r[4];
#pragma unroll
    for (int pass = 0; pass < 4; ++pass) bias_r[pass] = bias[pass * 64 + (tid >> 3)];

    // staging geometry: tile = 32 rows x 128 float4; thread covers
    // rows r0+4p (r0 = tid>>7), cols [c4, c4+4) fp32 (c4 = (tid&127)*4)
    const int r0 = tid >> 7;
    const int c4 = (tid & 127) * 4;

    const int tiles = B_ROWS / MTILE;    // 2048
    int t = blockIdx.x;

    // prefetch tile 0
    float4 xq[8];
#pragma unroll
    for (int p = 0; p < 8; ++p)
        xq[p] = *(const float4*)(X + (size_t)(t * MTILE + r0 + 4 * p) * K_DIM + c4);

    for (; t < tiles; t += NBLK) {
        // ---- convert + stage into LDS ----
#pragma unroll
        for (int p = 0; p < 8; ++p) {
            ushort4 h;
            h.x = f2bf(xq[p].x); h.y = f2bf(xq[p].y);
            h.z = f2bf(xq[p].z); h.w = f2bf(xq[p].w);
            *(ushort4*)(&Ash[(r0 + 4 * p) * STRIDE + c4]) = h;
        }
        __syncthreads();

        // ---- prefetch next tile (overlaps compute + epilogue) ----
        int tn = t + NBLK;
        if (tn < tiles) {
#pragma unroll
            for (int p = 0; p < 8; ++p)
                xq[p] = *(const float4*)(X + (size_t)(tn * MTILE + r0 + 4 * p) * K_DIM + c4);
        }

        // ---- K-loop: D[ch][row] = W·X^T, bias in C-init ----
        floatx4 acc[2][2];
#pragma unroll
        for (int rt = 0; rt < 2; ++rt)
#pragma unroll
            for (int ct = 0; ct < 2; ++ct)
#pragma unroll
                for (int reg = 0; reg < 4; ++reg)
                    acc[rt][ct][reg] = blr[ct][reg];
#pragma unroll
        for (int kk = 0; kk < 16; ++kk) {
            short8 a0 = *(const short8*)&Ash[(l15)      * STRIDE + kk * 32 + quad * 8];
            short8 a1 = *(const short8*)&Ash[(16 + l15) * STRIDE + kk * 32 + quad * 8];
            acc[0][0] = __builtin_amdgcn_mfma_f32_16x16x32_bf16(bfr[0][kk], a0, acc[0][0], 0, 0, 0);
            acc[0][1] = __builtin_amdgcn_mfma_f32_16x16x32_bf16(bfr[1][kk], a0, acc[0][1], 0, 0, 0);
            acc[1][0] = __builtin_amdgcn_mfma_f32_16x16x32_bf16(bfr[0][kk], a1, acc[1][0], 0, 0, 0);
            acc[1][1] = __builtin_amdgcn_mfma_f32_16x16x32_bf16(bfr[1][kk], a1, acc[1][1], 0, 0, 0);
        }

        // ---- epilogue: groupnorm stats in-lane (8 chans) + 2-step quad reduce ----
#pragma unroll
        for (int rt = 0; rt < 2; ++rt) {
            // row = rt*16 + l15; lane holds chans {ct*16 + quad*4 + reg}
            float s = 0.f, ss = 0.f;
#pragma unroll
            for (int ct = 0; ct < 2; ++ct)
#pragma unroll
                for (int reg = 0; reg < 4; ++reg) {
                    float v = acc[rt][ct][reg];
                    s += v; ss = fmaf(v, v, ss);
                }
            s  += __shfl_xor(s, 16);  s  += __shfl_xor(s, 32);
            ss += __shfl_xor(ss, 16); ss += __shfl_xor(ss, 32);
            float mean = s * (1.0f / 32.0f);
            float var  = ss * (1.0f / 32.0f) - mean * mean;
            float inv  = rsqrtf(var + EPS);
            float mi   = mean * inv;
            float mn   = 1e30f;
#pragma unroll
            for (int ct = 0; ct < 2; ++ct)
#pragma unroll
                for (int reg = 0; reg < 4; ++reg) {
                    float tnorm = fmaf(acc[rt][ct][reg], inv, -mi);
                    float g = fmaf(tnorm, wgr[ct][reg], bgr[ct][reg]);
                    mn = fminf(mn, g);
                }
            mn = fminf(mn, __shfl_xor(mn, 16));
            mn = fminf(mn, __shfl_xor(mn, 32));
            if (quad == 0) sm_min[wave][rt * 16 + l15] = mn;
        }
        __syncthreads();
        if (tid < MTILE) {
            float m0 = sm_min[0][tid];
#pragma unroll
            for (int w = 1; w < 8; ++w) m0 = fminf(m0, sm_min[w][tid]);
            m_sh[tid] = m0;
        }
        __syncthreads();

        // ---- broadcast write: out[c*B + t*32 + j] = m[j] + bias[c] ----
        float4 mv = *(const float4*)&m_sh[(tid & 7) * 4];
#pragma unroll
        for (int pass = 0; pass < 4; ++pass) {
            int c = pass * 64 + (tid >> 3);
            float bc = bias_r[pass];
            float4 o;
            o.x = mv.x + bc; o.y = mv.y + bc; o.z = mv.z + bc; o.w = mv.w + bc;
            *(float4*)(out + (size_t)c * B_ROWS + t * MTILE + (tid & 7) * 4) = o;
        }
        // next iteration's Ash write is safe: every wave passed the two
        // epilogue barriers, which postdate all Ash reads.
    }
}

extern "C" void kernel_launch(void* const* d_in, const int* in_sizes, int n_in,
                              void* d_out, int out_size, void* d_ws, size_t ws_size,
                              hipStream_t stream) {
    const float* x    = (const float*)d_in[0];
    const float* w    = (const float*)d_in[1];
    const float* bl   = (const float*)d_in[2];
    const float* wg   = (const float*)d_in[3];
    const float* bg   = (const float*)d_in[4];
    const float* bias = (const float*)d_in[5];

    unsigned short* P = (unsigned short*)d_ws;     // 256 KB packed bf16 W
    float* out = (float*)d_out;

    hipLaunchKernelGGL(pack_w, dim3(256), dim3(64), 0, stream, w, P);
    hipLaunchKernelGGL(fused_persistent, dim3(NBLK), dim3(512), 0, stream,
                       x, P, bl, wg, bg, bias, out);
}

// Round 4
// 229.940 us; speedup vs baseline: 1.0710x; 1.0114x over previous
//
#include <hip/hip_runtime.h>
#include <hip/hip_bf16.h>

// h = x(65536x512) @ W^T(512x256) + bias_lin ; GroupNorm(8 groups of 32)
// ; min over 256 channels -> m[b] ; out[c*B+b] = m[b] + bias[c]
//
// R4 design: the R0-R3 structure was register-capped at ONE 8-wave block/CU
// (bfr=128 VGPR of W per wave + acc -> ~230+ unified regs/wave -> 8 waves/CU),
// so every __syncthreads drained the whole CU (occupancy ~20% at any grid).
// New structure: 1024-thread blocks, 16 waves, each wave owns 16 channels
// (bfr = 16 short8 = 64 regs; total ~120/wave -> 16 waves/CU resident,
// enforced by __launch_bounds__(1024)). LDS X-tile is double-buffered
// (2 x 33.3 KB): staging tile t+1 overlaps the K-loop on tile t; the
// epilogue barriers provide all cross-iteration ordering (no stage barrier).
// GroupNorm group (32 ch) spans a wave pair -> stats combined via a small
// LDS exchange; min via per-wave LDS + 16-way combine; single-pass out write.
#define B_ROWS 65536
#define K_DIM  512
#define N_DIM  256
#define EPS    1e-5f
#define MTILE  32
#define NBLK   256
#define TILES  (B_ROWS / MTILE)
#define STRIDE 520      // 512 + 8 pad (bf16); dword-stride 260 -> ~2-way max on b128 reads (free)

using short8  = __attribute__((ext_vector_type(8))) short;
using floatx4 = __attribute__((ext_vector_type(4))) float;

__device__ __forceinline__ unsigned short f2bf(float f) {
    unsigned u = __builtin_bit_cast(unsigned, f);
    u += 0x7FFFu + ((u >> 16) & 1u);     // RNE
    return (unsigned short)(u >> 16);
}

// Pack W (256x512 fp32) into bf16 MFMA fragment order (A/B layouts symmetric
// for 16x16x32):
// P[((nt*16 + kkg)*64 + lane)*8 + j] = bf16(W[nt*16 + (lane&15)][kkg*32 + (lane>>4)*8 + j])
__global__ __launch_bounds__(64) void pack_w(const float* __restrict__ W,
                                             unsigned short* __restrict__ P) {
    int b    = blockIdx.x;           // 0..255
    int nt   = b >> 4, kk = b & 15;
    int lane = threadIdx.x;
    int l15  = lane & 15, quad = lane >> 4;
    const float* src = W + (size_t)(nt * 16 + l15) * K_DIM + kk * 32 + quad * 8;
    short8 v;
#pragma unroll
    for (int j = 0; j < 8; ++j) v[j] = (short)f2bf(src[j]);
    *(short8*)(P + ((size_t)(nt * 16 + kk) * 64 + lane) * 8) = v;
}

__global__ __launch_bounds__(1024) void fused_persistent(
    const float* __restrict__ X, const unsigned short* __restrict__ P,
    const float* __restrict__ bias_lin, const float* __restrict__ wgn,
    const float* __restrict__ bgn, const float* __restrict__ bias,
    float* __restrict__ out)
{
    __shared__ unsigned short Ash[2][MTILE * STRIDE];   // 2 x 33280 B
    __shared__ float smS[16][32];                        // per-wave partial sums
    __shared__ float smSS[16][32];
    __shared__ float smin[16][32];                       // per-wave 16-ch min
    __shared__ float m_sh[MTILE];

    const int tid  = threadIdx.x;
    const int wave = tid >> 6;            // 0..15; owns channels [16*wave, 16*wave+16)
    const int lane = tid & 63;
    const int l15  = lane & 15, quad = lane >> 4;

    // ---- this wave's W fragments: 16 short8 = 64 VGPRs (nt == wave) ----
    short8 bfr[16];
#pragma unroll
    for (int kkg = 0; kkg < 16; ++kkg)
        bfr[kkg] = *(const short8*)(P + (((size_t)wave * 16 + kkg) * 64 + lane) * 8);

    // per-lane channel params: ch = wave*16 + quad*4 + r
    float blr[4], wgr[4], bgr[4];
#pragma unroll
    for (int r = 0; r < 4; ++r) {
        int c = wave * 16 + quad * 4 + r;
        blr[r] = bias_lin[c]; wgr[r] = wgn[c]; bgr[r] = bgn[c];
    }
    const float bias_c = bias[tid >> 2];   // out channel for this thread

    // staging geometry: tile = 32 rows x 128 float4; thread covers rows
    // r0..r0+3 (r0 = (tid>>7)*4) at fp32 cols [c4, c4+4)
    const int r0 = (tid >> 7) * 4;
    const int c4 = (tid & 127) * 4;

    int t = blockIdx.x;

    // prologue: load + stage tile t into buf0, issue prefetch of t+NBLK
    float4 xq[4];
#pragma unroll
    for (int p = 0; p < 4; ++p)
        xq[p] = *(const float4*)(X + (size_t)(t * MTILE + r0 + p) * K_DIM + c4);
#pragma unroll
    for (int p = 0; p < 4; ++p) {
        ushort4 h;
        h.x = f2bf(xq[p].x); h.y = f2bf(xq[p].y);
        h.z = f2bf(xq[p].z); h.w = f2bf(xq[p].w);
        *(ushort4*)(&Ash[0][(r0 + p) * STRIDE + c4]) = h;
    }
    if (t + NBLK < TILES) {
#pragma unroll
        for (int p = 0; p < 4; ++p)
            xq[p] = *(const float4*)(X + (size_t)((t + NBLK) * MTILE + r0 + p) * K_DIM + c4);
    }
    __syncthreads();

    int cur = 0;
    for (; t < TILES; t += NBLK) {
        // ---- stage NEXT tile into the other buffer (overlaps this K-loop),
        //      then issue prefetch for t+2*NBLK ----
        if (t + NBLK < TILES) {
#pragma unroll
            for (int p = 0; p < 4; ++p) {
                ushort4 h;
                h.x = f2bf(xq[p].x); h.y = f2bf(xq[p].y);
                h.z = f2bf(xq[p].z); h.w = f2bf(xq[p].w);
                *(ushort4*)(&Ash[cur ^ 1][(r0 + p) * STRIDE + c4]) = h;
            }
            if (t + 2 * NBLK < TILES) {
#pragma unroll
                for (int p = 0; p < 4; ++p)
                    xq[p] = *(const float4*)(X + (size_t)((t + 2 * NBLK) * MTILE + r0 + p) * K_DIM + c4);
            }
        }

        // ---- K-loop on current buffer: D[ch16][row32] = W·X^T, bias in C-init ----
        floatx4 acc[2];
#pragma unroll
        for (int rt = 0; rt < 2; ++rt)
#pragma unroll
            for (int r = 0; r < 4; ++r) acc[rt][r] = blr[r];
#pragma unroll
        for (int kk = 0; kk < 16; ++kk) {
            short8 a0 = *(const short8*)&Ash[cur][(l15)      * STRIDE + kk * 32 + quad * 8];
            short8 a1 = *(const short8*)&Ash[cur][(16 + l15) * STRIDE + kk * 32 + quad * 8];
            acc[0] = __builtin_amdgcn_mfma_f32_16x16x32_bf16(bfr[kk], a0, acc[0], 0, 0, 0);
            acc[1] = __builtin_amdgcn_mfma_f32_16x16x32_bf16(bfr[kk], a1, acc[1], 0, 0, 0);
        }

        // ---- GroupNorm stats: in-lane over 4 ch + quad shfl -> wave's 16 ch;
        //      combine with partner wave (wave^1) via LDS ----
        float sreg[2], ssreg[2];
#pragma unroll
        for (int rt = 0; rt < 2; ++rt) {
            float s = 0.f, ss = 0.f;
#pragma unroll
            for (int r = 0; r < 4; ++r) { float v = acc[rt][r]; s += v; ss = fmaf(v, v, ss); }
            s  += __shfl_xor(s, 16);  s  += __shfl_xor(s, 32);
            ss += __shfl_xor(ss, 16); ss += __shfl_xor(ss, 32);
            sreg[rt] = s; ssreg[rt] = ss;
            if (quad == 0) { smS[wave][rt * 16 + l15] = s; smSS[wave][rt * 16 + l15] = ss; }
        }
        __syncthreads();

#pragma unroll
        for (int rt = 0; rt < 2; ++rt) {
            int row = rt * 16 + l15;
            float st   = sreg[rt]  + smS[wave ^ 1][row];    // 32-ch sums
            float sst  = ssreg[rt] + smSS[wave ^ 1][row];
            float mean = st * (1.0f / 32.0f);
            float var  = sst * (1.0f / 32.0f) - mean * mean;
            float inv  = rsqrtf(var + EPS);
            float mi   = mean * inv;
            float mn   = 1e30f;
#pragma unroll
            for (int r = 0; r < 4; ++r) {
                float g = fmaf(fmaf(acc[rt][r], inv, -mi), wgr[r], bgr[r]);
                mn = fminf(mn, g);
            }
            mn = fminf(mn, __shfl_xor(mn, 16));
            mn = fminf(mn, __shfl_xor(mn, 32));
            if (quad == 0) smin[wave][row] = mn;
        }
        __syncthreads();

        if (tid < MTILE) {
            float m0 = smin[0][tid];
#pragma unroll
            for (int w = 1; w < 16; ++w) m0 = fminf(m0, smin[w][tid]);
            m_sh[tid] = m0;
        }
        __syncthreads();

        // ---- single-pass broadcast write: thread -> channel c = tid>>2,
        //      rows [j0, j0+8) with j0 = (tid&3)*8 ----
        {
            int c  = tid >> 2;
            int j0 = (tid & 3) * 8;
            float4 ma = *(const float4*)&m_sh[j0];
            float4 mb = *(const float4*)&m_sh[j0 + 4];
            float4 oa, ob;
            oa.x = ma.x + bias_c; oa.y = ma.y + bias_c; oa.z = ma.z + bias_c; oa.w = ma.w + bias_c;
            ob.x = mb.x + bias_c; ob.y = mb.y + bias_c; ob.z = mb.z + bias_c; ob.w = mb.w + bias_c;
            float* dst = out + (size_t)c * B_ROWS + t * MTILE + j0;
            *(float4*)dst       = oa;
            *(float4*)(dst + 4) = ob;
        }
        cur ^= 1;
        // ordering: this iter's staging writes (buf cur^1) happen-before the
        // three barriers above, so next iter's K-loop reads are safe; this
        // iter's K-loop reads of buf cur finished before the first barrier,
        // so next iter's staging overwrite of buf cur is safe.
    }
}

extern "C" void kernel_launch(void* const* d_in, const int* in_sizes, int n_in,
                              void* d_out, int out_size, void* d_ws, size_t ws_size,
                              hipStream_t stream) {
    const float* x    = (const float*)d_in[0];
    const float* w    = (const float*)d_in[1];
    const float* bl   = (const float*)d_in[2];
    const float* wg   = (const float*)d_in[3];
    const float* bg   = (const float*)d_in[4];
    const float* bias = (const float*)d_in[5];

    unsigned short* P = (unsigned short*)d_ws;     // 256 KB packed bf16 W
    float* out = (float*)d_out;

    hipLaunchKernelGGL(pack_w, dim3(256), dim3(64), 0, stream, w, P);
    hipLaunchKernelGGL(fused_persistent, dim3(NBLK), dim3(1024), 0, stream,
                       x, P, bl, wg, bg, bias, out);
}

// Round 5
// 229.526 us; speedup vs baseline: 1.0729x; 1.0018x over previous
//
#include <hip/hip_runtime.h>
#include <hip/hip_bf16.h>

// h = x(65536x512) @ W^T(512x256) + bias_lin ; GroupNorm(8 groups of 32)
// ; min over 256 channels -> m[b] ; out[c*B+b] = m[b] + bias[c]
//
// R5 change (theory: __syncthreads' implicit s_waitcnt vmcnt(0) drains the
// t+2 prefetch loads at every epilogue barrier -> every iteration eats the
// full HBM queue latency on the critical path; explains dur/BW invariance
// across R0/R4 occupancy changes). All intra-loop barriers only order LDS
// (stats exchange, min exchange, Ash double-buffer handoff), so replace
// __syncthreads with s_waitcnt lgkmcnt(0) + raw s_barrier (T4: never drain
// vmcnt mid-loop). Prefetch loads now stay in flight across barriers; the
// compiler emits a counted vmcnt before xq's USE (next iter's staging).
// Structure otherwise identical to R4: 256 blocks x 1024 threads (16 waves,
// wave owns 16 channels, bfr = 16 short8), double-buffered Ash.
#define B_ROWS 65536
#define K_DIM  512
#define N_DIM  256
#define EPS    1e-5f
#define MTILE  32
#define NBLK   256
#define TILES  (B_ROWS / MTILE)
#define STRIDE 520      // 512 + 8 pad (bf16); ~4 conflict cyc per b128 read (~8% LDS overhead, acceptable)

using short8  = __attribute__((ext_vector_type(8))) short;
using floatx4 = __attribute__((ext_vector_type(4))) float;

// LDS-only barrier: does NOT drain vmcnt (rule 18: sched_barrier fences keep
// the compiler from hoisting dependent ops across the inline-asm waitcnt).
#define LBAR() do {                                          \
    __builtin_amdgcn_sched_barrier(0);                       \
    asm volatile("s_waitcnt lgkmcnt(0)" ::: "memory");       \
    __builtin_amdgcn_s_barrier();                            \
    __builtin_amdgcn_sched_barrier(0);                       \
} while (0)

__device__ __forceinline__ unsigned short f2bf(float f) {
    unsigned u = __builtin_bit_cast(unsigned, f);
    u += 0x7FFFu + ((u >> 16) & 1u);     // RNE
    return (unsigned short)(u >> 16);
}

// Pack W (256x512 fp32) into bf16 MFMA fragment order (A/B layouts symmetric
// for 16x16x32):
// P[((nt*16 + kkg)*64 + lane)*8 + j] = bf16(W[nt*16 + (lane&15)][kkg*32 + (lane>>4)*8 + j])
__global__ __launch_bounds__(64) void pack_w(const float* __restrict__ W,
                                             unsigned short* __restrict__ P) {
    int b    = blockIdx.x;           // 0..255
    int nt   = b >> 4, kk = b & 15;
    int lane = threadIdx.x;
    int l15  = lane & 15, quad = lane >> 4;
    const float* src = W + (size_t)(nt * 16 + l15) * K_DIM + kk * 32 + quad * 8;
    short8 v;
#pragma unroll
    for (int j = 0; j < 8; ++j) v[j] = (short)f2bf(src[j]);
    *(short8*)(P + ((size_t)(nt * 16 + kk) * 64 + lane) * 8) = v;
}

__global__ __launch_bounds__(1024) void fused_persistent(
    const float* __restrict__ X, const unsigned short* __restrict__ P,
    const float* __restrict__ bias_lin, const float* __restrict__ wgn,
    const float* __restrict__ bgn, const float* __restrict__ bias,
    float* __restrict__ out)
{
    __shared__ unsigned short Ash[2][MTILE * STRIDE];   // 2 x 33280 B
    __shared__ float smS[16][32];                        // per-wave partial sums
    __shared__ float smSS[16][32];
    __shared__ float smin[16][32];                       // per-wave 16-ch min
    __shared__ float m_sh[MTILE];

    const int tid  = threadIdx.x;
    const int wave = tid >> 6;            // 0..15; owns channels [16*wave, 16*wave+16)
    const int lane = tid & 63;
    const int l15  = lane & 15, quad = lane >> 4;

    // ---- this wave's W fragments: 16 short8 (nt == wave) ----
    short8 bfr[16];
#pragma unroll
    for (int kkg = 0; kkg < 16; ++kkg)
        bfr[kkg] = *(const short8*)(P + (((size_t)wave * 16 + kkg) * 64 + lane) * 8);

    // per-lane channel params: ch = wave*16 + quad*4 + r
    float blr[4], wgr[4], bgr[4];
#pragma unroll
    for (int r = 0; r < 4; ++r) {
        int c = wave * 16 + quad * 4 + r;
        blr[r] = bias_lin[c]; wgr[r] = wgn[c]; bgr[r] = bgn[c];
    }
    const float bias_c = bias[tid >> 2];   // out channel for this thread

    // staging geometry: tile = 32 rows x 128 float4; thread covers rows
    // r0..r0+3 (r0 = (tid>>7)*4) at fp32 cols [c4, c4+4)
    const int r0 = (tid >> 7) * 4;
    const int c4 = (tid & 127) * 4;

    int t = blockIdx.x;

    // prologue: load + stage tile t into buf0, issue prefetch of t+NBLK
    float4 xq[4];
#pragma unroll
    for (int p = 0; p < 4; ++p)
        xq[p] = *(const float4*)(X + (size_t)(t * MTILE + r0 + p) * K_DIM + c4);
#pragma unroll
    for (int p = 0; p < 4; ++p) {
        ushort4 h;
        h.x = f2bf(xq[p].x); h.y = f2bf(xq[p].y);
        h.z = f2bf(xq[p].z); h.w = f2bf(xq[p].w);
        *(ushort4*)(&Ash[0][(r0 + p) * STRIDE + c4]) = h;
    }
    if (t + NBLK < TILES) {
#pragma unroll
        for (int p = 0; p < 4; ++p)
            xq[p] = *(const float4*)(X + (size_t)((t + NBLK) * MTILE + r0 + p) * K_DIM + c4);
    }
    LBAR();

    int cur = 0;
    for (; t < TILES; t += NBLK) {
        // ---- stage NEXT tile into the other buffer (overlaps this K-loop),
        //      then issue prefetch for t+2*NBLK ----
        if (t + NBLK < TILES) {
#pragma unroll
            for (int p = 0; p < 4; ++p) {
                ushort4 h;
                h.x = f2bf(xq[p].x); h.y = f2bf(xq[p].y);
                h.z = f2bf(xq[p].z); h.w = f2bf(xq[p].w);
                *(ushort4*)(&Ash[cur ^ 1][(r0 + p) * STRIDE + c4]) = h;
            }
            if (t + 2 * NBLK < TILES) {
#pragma unroll
                for (int p = 0; p < 4; ++p)
                    xq[p] = *(const float4*)(X + (size_t)((t + 2 * NBLK) * MTILE + r0 + p) * K_DIM + c4);
            }
        }

        // ---- K-loop on current buffer: D[ch16][row32] = W·X^T, bias in C-init ----
        floatx4 acc[2];
#pragma unroll
        for (int rt = 0; rt < 2; ++rt)
#pragma unroll
            for (int r = 0; r < 4; ++r) acc[rt][r] = blr[r];
#pragma unroll
        for (int kk = 0; kk < 16; ++kk) {
            short8 a0 = *(const short8*)&Ash[cur][(l15)      * STRIDE + kk * 32 + quad * 8];
            short8 a1 = *(const short8*)&Ash[cur][(16 + l15) * STRIDE + kk * 32 + quad * 8];
            acc[0] = __builtin_amdgcn_mfma_f32_16x16x32_bf16(bfr[kk], a0, acc[0], 0, 0, 0);
            acc[1] = __builtin_amdgcn_mfma_f32_16x16x32_bf16(bfr[kk], a1, acc[1], 0, 0, 0);
        }

        // ---- GroupNorm stats: in-lane over 4 ch + quad shfl -> wave's 16 ch;
        //      combine with partner wave (wave^1) via LDS ----
        float sreg[2], ssreg[2];
#pragma unroll
        for (int rt = 0; rt < 2; ++rt) {
            float s = 0.f, ss = 0.f;
#pragma unroll
            for (int r = 0; r < 4; ++r) { float v = acc[rt][r]; s += v; ss = fmaf(v, v, ss); }
            s  += __shfl_xor(s, 16);  s  += __shfl_xor(s, 32);
            ss += __shfl_xor(ss, 16); ss += __shfl_xor(ss, 32);
            sreg[rt] = s; ssreg[rt] = ss;
            if (quad == 0) { smS[wave][rt * 16 + l15] = s; smSS[wave][rt * 16 + l15] = ss; }
        }
        LBAR();

#pragma unroll
        for (int rt = 0; rt < 2; ++rt) {
            int row = rt * 16 + l15;
            float st   = sreg[rt]  + smS[wave ^ 1][row];    // 32-ch sums
            float sst  = ssreg[rt] + smSS[wave ^ 1][row];
            float mean = st * (1.0f / 32.0f);
            float var  = sst * (1.0f / 32.0f) - mean * mean;
            float inv  = rsqrtf(var + EPS);
            float mi   = mean * inv;
            float mn   = 1e30f;
#pragma unroll
            for (int r = 0; r < 4; ++r) {
                float g = fmaf(fmaf(acc[rt][r], inv, -mi), wgr[r], bgr[r]);
                mn = fminf(mn, g);
            }
            mn = fminf(mn, __shfl_xor(mn, 16));
            mn = fminf(mn, __shfl_xor(mn, 32));
            if (quad == 0) smin[wave][row] = mn;
        }
        LBAR();

        if (tid < MTILE) {
            float m0 = smin[0][tid];
#pragma unroll
            for (int w = 1; w < 16; ++w) m0 = fminf(m0, smin[w][tid]);
            m_sh[tid] = m0;
        }
        LBAR();

        // ---- single-pass broadcast write: thread -> channel c = tid>>2,
        //      rows [j0, j0+8) with j0 = (tid&3)*8 ----
        {
            int c  = tid >> 2;
            int j0 = (tid & 3) * 8;
            float4 ma = *(const float4*)&m_sh[j0];
            float4 mb = *(const float4*)&m_sh[j0 + 4];
            float4 oa, ob;
            oa.x = ma.x + bias_c; oa.y = ma.y + bias_c; oa.z = ma.z + bias_c; oa.w = ma.w + bias_c;
            ob.x = mb.x + bias_c; ob.y = mb.y + bias_c; ob.z = mb.z + bias_c; ob.w = mb.w + bias_c;
            float* dst = out + (size_t)c * B_ROWS + t * MTILE + j0;
            *(float4*)dst       = oa;
            *(float4*)(dst + 4) = ob;
        }
        cur ^= 1;
        // ordering: Ash handoff is covered by the three lgkmcnt(0)+s_barrier
        // points above (all ds ops drained per-wave before each barrier);
        // global loads/stores need no intra-loop ordering (prefetch regs are
        // guarded by compiler-inserted counted vmcnt at their use; stores go
        // to disjoint addresses).
    }
}

extern "C" void kernel_launch(void* const* d_in, const int* in_sizes, int n_in,
                              void* d_out, int out_size, void* d_ws, size_t ws_size,
                              hipStream_t stream) {
    const float* x    = (const float*)d_in[0];
    const float* w    = (const float*)d_in[1];
    const float* bl   = (const float*)d_in[2];
    const float* wg   = (const float*)d_in[3];
    const float* bg   = (const float*)d_in[4];
    const float* bias = (const float*)d_in[5];

    unsigned short* P = (unsigned short*)d_ws;     // 256 KB packed bf16 W
    float* out = (float*)d_out;

    hipLaunchKernelGGL(pack_w, dim3(256), dim3(64), 0, stream, w, P);
    hipLaunchKernelGGL(fused_persistent, dim3(NBLK), dim3(1024), 0, stream,
                       x, P, bl, wg, bg, bias, out);
}